// Round 10
// baseline (585.925 us; speedup 1.0000x reference)
//
#include <hip/hip_runtime.h>
#include <math.h>
#include <stdint.h>

// AttentionMC on MI355X: x(2,2048,1024) fp32; Wq/Wk/Wv/Wo(1024,1024) fp32.
// Split-bf16 (hi/lo, 3-term) MFMA. absmax 9.77e-4 (passed R3/R5/R6/R8).
// R9: qkv WRITE_SIZE (~1.4GB) tracks LOGICAL staged volume (fabric fill+victim,
// invariant to store mechanics/placement: R5/R6/R8). Cut the volume: 256x256
// tiles (192 blocks x 2MB staged = 384MB vs 768MB). Per-element k-order
// unchanged -> bit-identical outputs. attn/proj keep R8 swizzles (+40us).
// Pipeline: split_convert -> qkv_mfma(+RoPE, +V^T) -> attn_mfma -> proj_mfma.
// ws (80 MB): xhi xlo | whi wlo | qhi qlo khi klo | vthi vtlo
//   (xhi/xlo reused as attn-out hi/lo after qkv consumes x).

#define S_LEN 2048
#define NHEAD 16
#define HDIM  64
#define NBH   32

typedef __attribute__((ext_vector_type(8))) short  bf16x8;
typedef __attribute__((ext_vector_type(4))) float  f32x4;
typedef unsigned short u16;
typedef unsigned int   u32;

__device__ __forceinline__ u16 f2bf(float f) {          // RNE fp32->bf16 bits
    u32 u = __float_as_uint(f);
    return (u16)((u + 0x7FFFu + ((u >> 16) & 1u)) >> 16);
}
__device__ __forceinline__ float bf2f(u16 s) {
    return __uint_as_float(((u32)s) << 16);
}
__device__ __forceinline__ f32x4 mfma16(bf16x8 a, bf16x8 b, f32x4 c) {
    return __builtin_amdgcn_mfma_f32_16x16x32_bf16(a, b, c, 0, 0, 0);
}

// ---------------- 1. fp32 -> bf16 hi/lo split for x and all weights ----------------
__global__ __launch_bounds__(256)
void split_convert(const float* __restrict__ x,
                   const float* __restrict__ Wq, const float* __restrict__ Wk,
                   const float* __restrict__ Wv, const float* __restrict__ Wo,
                   u16* __restrict__ xhi, u16* __restrict__ xlo,
                   u16* __restrict__ whi, u16* __restrict__ wlo)
{
    const int g = blockIdx.x * 256 + threadIdx.x;   // float4 index, 2M total
    const float* src; u16 *dhi, *dlo; int loc;
    if (g < 1048576) { src = x; dhi = xhi; dlo = xlo; loc = g; }
    else {
        const int r = g - 1048576;
        const int wsel = r >> 18;                   // 256K float4 per weight
        loc = r & 262143;
        src = (wsel == 0) ? Wq : (wsel == 1) ? Wk : (wsel == 2) ? Wv : Wo;
        dhi = whi + ((size_t)wsel << 20);
        dlo = wlo + ((size_t)wsel << 20);
    }
    const float4 v = reinterpret_cast<const float4*>(src)[loc];
    ushort4 hv, lv;
    hv.x = f2bf(v.x); lv.x = f2bf(v.x - bf2f(hv.x));
    hv.y = f2bf(v.y); lv.y = f2bf(v.y - bf2f(hv.y));
    hv.z = f2bf(v.z); lv.z = f2bf(v.z - bf2f(hv.z));
    hv.w = f2bf(v.w); lv.w = f2bf(v.w - bf2f(hv.w));
    reinterpret_cast<ushort4*>(dhi)[loc] = hv;
    reinterpret_cast<ushort4*>(dlo)[loc] = lv;
}

// ---------------- 2. QKV projection GEMM, 256x256 tile (hi/lo MFMA) ----------------
// M=4096, Nglobal=3072 (q|k|v), K=1024. Grid (nb=12, mb=16), 512 thr = 8 waves
// (2M x 4N, wave tile 128x64 = one head wide). BK=32, reg-staged 2-phase prefetch.
// LDS 64KB: Ah|Al|Bh|Bl as [256][32] u16 @ 0/8192/16384/24576.
__global__ __launch_bounds__(512, 2)
void qkv_mfma(const u16* __restrict__ xhi, const u16* __restrict__ xlo,
              const u16* __restrict__ whi, const u16* __restrict__ wlo,
              u16* __restrict__ qhi, u16* __restrict__ qlo,
              u16* __restrict__ khi, u16* __restrict__ klo,
              u16* __restrict__ vthi, u16* __restrict__ vtlo)
{
    __shared__ __align__(16) u16 SMEM[32768];   // 65536 B
    const int tid = threadIdx.x, lane = tid & 63, w = tid >> 6;
    const int l15 = lane & 15, l16 = lane >> 4;
    const int wr = w >> 2, wc = w & 3;          // wave tile (2M x 4N)
    const int nb = blockIdx.x;                  // 0..11
    const int mb = blockIdx.y;                  // 0..15
    const int m0 = mb * 256;
    const int tsel = nb >> 2;                   // 0=q 1=k 2=v
    const int nloc0 = (nb & 3) * 256;
    const u16* __restrict__ Wh = whi + ((size_t)tsel << 20);
    const u16* __restrict__ Wl = wlo + ((size_t)tsel << 20);

    // staging: 1024 uint4-slots per tensor; thread handles slots {tid, tid+512}
    const int r0 = tid >> 2, r1 = r0 + 128;     // rows 0..255
    const int c0 = (tid & 3) * 8;               // u16 col 0/8/16/24

    f32x4 acc[8][4];
    #pragma unroll
    for (int i = 0; i < 8; ++i)
        #pragma unroll
        for (int j = 0; j < 4; ++j) acc[i][j] = (f32x4){0.f, 0.f, 0.f, 0.f};

    uint4 Ah0, Ah1, Al0, Al1, Bh0, Bh1, Bl0, Bl1;
    {
        const size_t a0 = (size_t)(m0 + r0) * 1024 + c0;
        const size_t a1 = (size_t)(m0 + r1) * 1024 + c0;
        const size_t b0 = (size_t)(nloc0 + r0) * 1024 + c0;
        const size_t b1 = (size_t)(nloc0 + r1) * 1024 + c0;
        Ah0 = *(const uint4*)&xhi[a0]; Ah1 = *(const uint4*)&xhi[a1];
        Al0 = *(const uint4*)&xlo[a0]; Al1 = *(const uint4*)&xlo[a1];
        Bh0 = *(const uint4*)&Wh[b0];  Bh1 = *(const uint4*)&Wh[b1];
        Bl0 = *(const uint4*)&Wl[b0];  Bl1 = *(const uint4*)&Wl[b1];
    }

    for (int k0 = 0; k0 < 1024; k0 += 32) {
        __syncthreads();                          // prev tile's frag reads done
        *(uint4*)&SMEM[        r0 * 32 + c0] = Ah0;
        *(uint4*)&SMEM[        r1 * 32 + c0] = Ah1;
        *(uint4*)&SMEM[ 8192 + r0 * 32 + c0] = Al0;
        *(uint4*)&SMEM[ 8192 + r1 * 32 + c0] = Al1;
        *(uint4*)&SMEM[16384 + r0 * 32 + c0] = Bh0;
        *(uint4*)&SMEM[16384 + r1 * 32 + c0] = Bh1;
        *(uint4*)&SMEM[24576 + r0 * 32 + c0] = Bl0;
        *(uint4*)&SMEM[24576 + r1 * 32 + c0] = Bl1;
        __syncthreads();                          // tile visible to all waves
        if (k0 + 32 < 1024) {                     // prefetch next tile under MFMA
            const int kn = k0 + 32;
            const size_t a0 = (size_t)(m0 + r0) * 1024 + kn + c0;
            const size_t a1 = (size_t)(m0 + r1) * 1024 + kn + c0;
            const size_t b0 = (size_t)(nloc0 + r0) * 1024 + kn + c0;
            const size_t b1 = (size_t)(nloc0 + r1) * 1024 + kn + c0;
            Ah0 = *(const uint4*)&xhi[a0]; Ah1 = *(const uint4*)&xhi[a1];
            Al0 = *(const uint4*)&xlo[a0]; Al1 = *(const uint4*)&xlo[a1];
            Bh0 = *(const uint4*)&Wh[b0];  Bh1 = *(const uint4*)&Wh[b1];
            Bl0 = *(const uint4*)&Wl[b0];  Bl1 = *(const uint4*)&Wl[b1];
        }
        bf16x8 b_h[4], b_l[4];
        #pragma unroll
        for (int j = 0; j < 4; ++j) {
            const int bo = 16384 + (wc * 64 + j * 16 + l15) * 32 + l16 * 8;
            b_h[j] = *(const bf16x8*)&SMEM[bo];
            b_l[j] = *(const bf16x8*)&SMEM[bo + 8192];
        }
        #pragma unroll
        for (int i = 0; i < 8; ++i) {
            const int ao = (wr * 128 + i * 16 + l15) * 32 + l16 * 8;
            const bf16x8 a_h = *(const bf16x8*)&SMEM[ao];
            const bf16x8 a_l = *(const bf16x8*)&SMEM[ao + 8192];
            #pragma unroll
            for (int j = 0; j < 4; ++j) {
                acc[i][j] = mfma16(a_h, b_h[j], acc[i][j]);
                acc[i][j] = mfma16(a_h, b_l[j], acc[i][j]);
                acc[i][j] = mfma16(a_l, b_h[j], acc[i][j]);
            }
        }
    }

    // ---- epilogue: per-wave 128x64 (one head), LDS-staged coalesced stores ----
    __syncthreads();                         // all waves done reading SMEM
    const int hh = (nb & 3) * 4 + wc;        // head 0..15
    const int m0w = m0 + wr * 128;           // never straddles batch (128 | 2048)
    const int b = m0w >> 11, sb0 = m0w & 2047;
    u16* const chunk = SMEM + w * 4096;      // 8192 B per wave

    if (tsel < 2) {
        u16* __restrict__ dh = tsel ? khi : qhi;
        u16* __restrict__ dl = tsel ? klo : qlo;
        const float scl = tsel ? 1.0f : 0.125f;   // fold 1/sqrt(hd) into q
        const float inv0 = (float)exp((double)l15        * -0.28782313662425574);
        const float inv1 = (float)exp((double)(l15 + 16) * -0.28782313662425574);
        u16* const Thi = chunk;              // [16][72]
        u16* const Tlo = chunk + 1152;
        #pragma unroll
        for (int i = 0; i < 8; ++i) {        // 16-row passes
            #pragma unroll
            for (int e = 0; e < 4; ++e) {
                const int rl = l16 * 4 + e;
                const int s = sb0 + i * 16 + rl;
                #pragma unroll
                for (int j = 0; j < 2; ++j) {             // pair (d, d+32) = frags (j, j+2)
                    const float inv = j ? inv1 : inv0;
                    const float ang = (float)s * inv;
                    const float sn = sinf(ang), cs = cosf(ang);
                    const float x1 = acc[i][j][e], x2 = acc[i][j + 2][e];
                    const float o1 = (x1 * cs - x2 * sn) * scl;
                    const float o2 = (x1 * sn + x2 * cs) * scl;
                    const u16 h1 = f2bf(o1), h2 = f2bf(o2);
                    Thi[rl * 72 + j * 16 + l15]       = h1;
                    Tlo[rl * 72 + j * 16 + l15]       = f2bf(o1 - bf2f(h1));
                    Thi[rl * 72 + (j + 2) * 16 + l15] = h2;
                    Tlo[rl * 72 + (j + 2) * 16 + l15] = f2bf(o2 - bf2f(h2));
                }
            }
            #pragma unroll
            for (int p = 0; p < 2; ++p) {    // 16 rows x 128 B, full lines
                const int slot = p * 64 + lane;
                const int rr = slot >> 3, c8 = (slot & 7) * 8;
                const size_t ga = (((size_t)(b * NHEAD + hh) * S_LEN) + sb0 + i * 16 + rr) * HDIM + c8;
                *(uint4*)&dh[ga] = *(const uint4*)&Thi[rr * 72 + c8];
                *(uint4*)&dl[ga] = *(const uint4*)&Tlo[rr * 72 + c8];
            }
        }
    } else {
        // V: stage transposed (d-major) and store directly to V^T [bh][d][s]
        u16* const Thi = chunk;              // [64][24]
        u16* const Tlo = chunk + 1536;
        #pragma unroll
        for (int i = 0; i < 8; ++i) {        // 16-s passes
            #pragma unroll
            for (int e = 0; e < 4; ++e) {
                const int rl = l16 * 4 + e;               // s within pass
                #pragma unroll
                for (int j = 0; j < 4; ++j) {
                    const float o = acc[i][j][e];
                    const u16 hb = f2bf(o);
                    Thi[(j * 16 + l15) * 24 + rl] = hb;
                    Tlo[(j * 16 + l15) * 24 + rl] = f2bf(o - bf2f(hb));
                }
            }
            #pragma unroll
            for (int p = 0; p < 2; ++p) {    // 64 d-rows x 32 B
                const int slot = p * 64 + lane;
                const int dd = slot >> 1, s8 = (slot & 1) * 8;
                const size_t ga = (((size_t)(b * NHEAD + hh) * HDIM) + dd) * S_LEN + sb0 + i * 16 + s8;
                *(uint4*)&vthi[ga] = *(const uint4*)&Thi[dd * 24 + s8];
                *(uint4*)&vtlo[ga] = *(const uint4*)&Tlo[dd * 24 + s8];
            }
        }
    }
}

// ---------------- 3. causal flash attention (hi/lo MFMA) ----------------
// grid (32,32), 256 thr = 4 waves, wave w owns q-rows [qt*64+16w, +16).
// XCD swizzle: XCD k owns heads {4k..4k+3} (KV 4MB = L2-resident);
// within head, qt longest-first.
// LDS 54272 B flat: KH|KL|VH|VL (u16 [64][72] each) | PW (float [4][16][68]).
__global__ __launch_bounds__(256)
void attn_mfma(const u16* __restrict__ qhi, const u16* __restrict__ qlo,
               const u16* __restrict__ khi, const u16* __restrict__ klo,
               const u16* __restrict__ vthi, const u16* __restrict__ vtlo,
               u16* __restrict__ ohi, u16* __restrict__ olo)
{
    __shared__ __align__(16) u16 AS[27136];
    u16* const KH = AS;              // 4608 u16
    u16* const KL = AS + 4608;
    u16* const VH = AS + 9216;
    u16* const VL = AS + 13824;
    float* const PW = (float*)(AS + 18432);   // [4][16][68]
    const int tid = threadIdx.x, lane = tid & 63, w = tid >> 6;
    const int l15 = lane & 15, l16 = lane >> 4;
    // --- XCD-aware bijective remap (1024 = 8 XCD x 128) ---
    const int lin = blockIdx.y * 32 + blockIdx.x;
    const int xcd = lin & 7, idx = lin >> 3;      // idx 0..127
    const int bh = xcd * 4 + (idx >> 5);          // head 0..31 (XCD-striped)
    const int qt = 31 - (idx & 31);               // longest blocks first
    const size_t sbase = (size_t)bh * S_LEN * HDIM;   // [bh][s][d]
    const size_t dbase = (size_t)bh * HDIM * S_LEN;   // [bh][d][s]
    float* const pw = PW + w * 1088;

    // Q fragments hoisted for the whole kernel (q pre-scaled by 1/8)
    bf16x8 q_h[2], q_l[2];
    {
        const int s = qt * 64 + w * 16 + l15;
        #pragma unroll
        for (int ks = 0; ks < 2; ++ks) {
            const size_t ga = sbase + (size_t)s * HDIM + ks * 32 + l16 * 8;
            q_h[ks] = *(const bf16x8*)&qhi[ga];
            q_l[ks] = *(const bf16x8*)&qlo[ga];
        }
    }

    f32x4 oacc[4];
    #pragma unroll
    for (int t = 0; t < 4; ++t) oacc[t] = (f32x4){0.f, 0.f, 0.f, 0.f};
    float m_i[4], l_i[4];
    #pragma unroll
    for (int e = 0; e < 4; ++e) { m_i[e] = -INFINITY; l_i[e] = 0.f; }

    for (int kt = 0; kt <= qt; ++kt) {
        __syncthreads();                       // protect LDS K/V reuse
        #pragma unroll
        for (int p = 0; p < 2; ++p) {          // reg-stage K and V^T tiles
            const int c = tid + p * 256;       // 512 16B-chunks per tensor
            const int r = c >> 3, dc = (c & 7) * 8;
            const size_t gk = sbase + (size_t)(kt * 64 + r) * HDIM + dc;
            *(uint4*)&KH[r * 72 + dc] = *(const uint4*)&khi[gk];
            *(uint4*)&KL[r * 72 + dc] = *(const uint4*)&klo[gk];
            const size_t gv = dbase + (size_t)r * S_LEN + kt * 64 + dc;
            *(uint4*)&VH[r * 72 + dc] = *(const uint4*)&vthi[gv];
            *(uint4*)&VL[r * 72 + dc] = *(const uint4*)&vtlo[gv];
        }
        __syncthreads();

        // QK^T: scores[16 q-rows][64 k-cols] per wave
        f32x4 st[4];
        #pragma unroll
        for (int t = 0; t < 4; ++t) st[t] = (f32x4){0.f, 0.f, 0.f, 0.f};
        #pragma unroll
        for (int t = 0; t < 4; ++t)
            #pragma unroll
            for (int ks = 0; ks < 2; ++ks) {
                const bf16x8 kf_h = *(const bf16x8*)&KH[(t * 16 + l15) * 72 + ks * 32 + l16 * 8];
                const bf16x8 kf_l = *(const bf16x8*)&KL[(t * 16 + l15) * 72 + ks * 32 + l16 * 8];
                st[t] = mfma16(q_h[ks], kf_h, st[t]);
                st[t] = mfma16(q_h[ks], kf_l, st[t]);
                st[t] = mfma16(q_l[ks], kf_h, st[t]);
            }
        if (kt == qt) {                        // causal mask inside diagonal tile
            #pragma unroll
            for (int t = 0; t < 4; ++t)
                #pragma unroll
                for (int e = 0; e < 4; ++e)
                    if (t * 16 + l15 > w * 16 + l16 * 4 + e) st[t][e] = -1e30f;
        }
        // online softmax (rows live in D-layout: row = 4*l16+e, 16 lanes share a row)
        #pragma unroll
        for (int e = 0; e < 4; ++e) {
            float mx = fmaxf(fmaxf(st[0][e], st[1][e]), fmaxf(st[2][e], st[3][e]));
            #pragma unroll
            for (int msk = 8; msk >= 1; msk >>= 1) mx = fmaxf(mx, __shfl_xor(mx, msk));
            const float mn = fmaxf(m_i[e], mx);
            const float scl = __expf(m_i[e] - mn);
            float rs = 0.f;
            #pragma unroll
            for (int t = 0; t < 4; ++t) {
                const float p = __expf(st[t][e] - mn);
                st[t][e] = p; rs += p;
            }
            #pragma unroll
            for (int msk = 8; msk >= 1; msk >>= 1) rs += __shfl_xor(rs, msk);
            l_i[e] = l_i[e] * scl + rs;
            m_i[e] = mn;
            #pragma unroll
            for (int t = 0; t < 4; ++t) oacc[t][e] *= scl;
        }
        // P: D-layout regs -> wave-private LDS -> A-operand layout + hi/lo split
        #pragma unroll
        for (int t = 0; t < 4; ++t)
            #pragma unroll
            for (int e = 0; e < 4; ++e)
                pw[(l16 * 4 + e) * 68 + t * 16 + l15] = st[t][e];
        bf16x8 p_h[2], p_l[2];
        #pragma unroll
        for (int ks = 0; ks < 2; ++ks) {
            float pf[8];
            *(f32x4*)&pf[0] = *(const f32x4*)&pw[l15 * 68 + ks * 32 + l16 * 8];
            *(f32x4*)&pf[4] = *(const f32x4*)&pw[l15 * 68 + ks * 32 + l16 * 8 + 4];
            #pragma unroll
            for (int u = 0; u < 8; ++u) {
                const u16 hb = f2bf(pf[u]);
                p_h[ks][u] = (short)hb;
                p_l[ks][u] = (short)f2bf(pf[u] - bf2f(hb));
            }
        }
        // PV: out[m][d] += P[m][n] V[n][d]  (V^T tile, n contiguous)
        #pragma unroll
        for (int t = 0; t < 4; ++t)
            #pragma unroll
            for (int ks = 0; ks < 2; ++ks) {
                const bf16x8 vf_h = *(const bf16x8*)&VH[(t * 16 + l15) * 72 + ks * 32 + l16 * 8];
                const bf16x8 vf_l = *(const bf16x8*)&VL[(t * 16 + l15) * 72 + ks * 32 + l16 * 8];
                oacc[t] = mfma16(p_h[ks], vf_h, oacc[t]);
                oacc[t] = mfma16(p_h[ks], vf_l, oacc[t]);
                oacc[t] = mfma16(p_l[ks], vf_h, oacc[t]);
            }
    }
    // ---- epilogue: normalize, split hi/lo, LDS-staged coalesced store ----
    __syncthreads();                          // K/V LDS dead; alias staging over it
    u16* const Ohi = AS + w * 2304;           // [16][72] per wave
    u16* const Olo = Ohi + 1152;
    #pragma unroll
    for (int e = 0; e < 4; ++e) {
        const float invl = 1.f / l_i[e];
        const int rl = l16 * 4 + e;
        #pragma unroll
        for (int t = 0; t < 4; ++t) {
            const float o = oacc[t][e] * invl;
            const u16 hb = f2bf(o);
            Ohi[rl * 72 + t * 16 + l15] = hb;
            Olo[rl * 72 + t * 16 + l15] = f2bf(o - bf2f(hb));
        }
    }
    #pragma unroll
    for (int p = 0; p < 2; ++p) {             // 16 rows x 128B, full lines
        const int slot = p * 64 + lane;
        const int rr = slot >> 3, c8 = (slot & 7) * 8;
        const size_t ga = sbase + (size_t)(qt * 64 + w * 16 + rr) * HDIM + c8;
        *(uint4*)&ohi[ga] = *(const uint4*)&Ohi[rr * 72 + c8];
        *(uint4*)&olo[ga] = *(const uint4*)&Olo[rr * 72 + c8];
    }
}

// ---------------- 4. output projection: out = attn_out @ Wo^T (fp32 out) ----------------
// Reg-staged LDS fill, 2-phase prefetch. XCD swizzle: XCD k owns m-blocks
// {4k..4k+3}; within XCD consecutive blocks share the A-slab (A-hot).
__global__ __launch_bounds__(256)
void proj_mfma(const u16* __restrict__ ahi, const u16* __restrict__ alo,
               const u16* __restrict__ wohi, const u16* __restrict__ wolo,
               float* __restrict__ out)
{
    __shared__ __align__(16) u16 SMEM[16384];   // Ah|Al|Bh|Bl @ 0/4096/8192/12288 u16
    const int tid = threadIdx.x, lane = tid & 63, w = tid >> 6;
    const int l15 = lane & 15, l16 = lane >> 4;
    // --- XCD-aware bijective remap (256 = 8 XCD x 32) ---
    const int lin = blockIdx.y * 32 + blockIdx.x;
    const int xcd = lin & 7, idx = lin >> 3;     // idx 0..31
    const int mb = xcd * 4 + (idx >> 3);         // m-block 0..31 (XCD-striped)
    const int nb = idx & 7;                      // n-block 0..7 (A-slab hot)
    const int m0 = mb * 128, n0 = nb * 128;

    const int r0 = tid >> 2, r1 = r0 + 64;
    const int c0 = (tid & 3) * 8;
    // A-row geometry is k-independent
    const int ri0 = m0 + r0, ri1 = m0 + r1;
    const int ab0 = ri0 >> 11, as0 = ri0 & 2047;
    const int ab1 = ri1 >> 11, as1 = ri1 & 2047;

    f32x4 acc[4][4];
    #pragma unroll
    for (int i = 0; i < 4; ++i)
        #pragma unroll
        for (int j = 0; j < 4; ++j) acc[i][j] = (f32x4){0.f, 0.f, 0.f, 0.f};

    uint4 Ah0, Ah1, Al0, Al1, Bh0, Bh1, Bl0, Bl1;
    {
        const int kc = c0;                    // k0 = 0
        const int hh = kc >> 6, dd = kc & 63;
        const size_t a0 = ((size_t)(ab0 * NHEAD + hh) * S_LEN + as0) * HDIM + dd;
        const size_t a1 = ((size_t)(ab1 * NHEAD + hh) * S_LEN + as1) * HDIM + dd;
        const size_t b0 = (size_t)(n0 + r0) * 1024 + c0;
        const size_t b1 = (size_t)(n0 + r1) * 1024 + c0;
        Ah0 = *(const uint4*)&ahi[a0];  Ah1 = *(const uint4*)&ahi[a1];
        Al0 = *(const uint4*)&alo[a0];  Al1 = *(const uint4*)&alo[a1];
        Bh0 = *(const uint4*)&wohi[b0]; Bh1 = *(const uint4*)&wohi[b1];
        Bl0 = *(const uint4*)&wolo[b0]; Bl1 = *(const uint4*)&wolo[b1];
    }

    for (int k0 = 0; k0 < 1024; k0 += 32) {
        __syncthreads();
        *(uint4*)&SMEM[        r0 * 32 + c0] = Ah0;
        *(uint4*)&SMEM[        r1 * 32 + c0] = Ah1;
        *(uint4*)&SMEM[ 4096 + r0 * 32 + c0] = Al0;
        *(uint4*)&SMEM[ 4096 + r1 * 32 + c0] = Al1;
        *(uint4*)&SMEM[ 8192 + r0 * 32 + c0] = Bh0;
        *(uint4*)&SMEM[ 8192 + r1 * 32 + c0] = Bh1;
        *(uint4*)&SMEM[12288 + r0 * 32 + c0] = Bl0;
        *(uint4*)&SMEM[12288 + r1 * 32 + c0] = Bl1;
        __syncthreads();
        if (k0 + 32 < 1024) {
            const int kc = k0 + 32 + c0;
            const int hh = kc >> 6, dd = kc & 63;
            const size_t a0 = ((size_t)(ab0 * NHEAD + hh) * S_LEN + as0) * HDIM + dd;
            const size_t a1 = ((size_t)(ab1 * NHEAD + hh) * S_LEN + as1) * HDIM + dd;
            const size_t b0 = (size_t)(n0 + r0) * 1024 + k0 + 32 + c0;
            const size_t b1 = (size_t)(n0 + r1) * 1024 + k0 + 32 + c0;
            Ah0 = *(const uint4*)&ahi[a0];  Ah1 = *(const uint4*)&ahi[a1];
            Al0 = *(const uint4*)&alo[a0];  Al1 = *(const uint4*)&alo[a1];
            Bh0 = *(const uint4*)&wohi[b0]; Bh1 = *(const uint4*)&wohi[b1];
            Bl0 = *(const uint4*)&wolo[b0]; Bl1 = *(const uint4*)&wolo[b1];
        }
        const int mo = (w >> 1) * 64, no = (w & 1) * 64;
        bf16x8 a_h[4], a_l[4], b_h[4], b_l[4];
        #pragma unroll
        for (int f = 0; f < 4; ++f) {
            const int ao = (mo + f * 16 + l15) * 32 + l16 * 8;
            a_h[f] = *(const bf16x8*)&SMEM[ao];
            a_l[f] = *(const bf16x8*)&SMEM[4096 + ao];
            const int bo = (no + f * 16 + l15) * 32 + l16 * 8;
            b_h[f] = *(const bf16x8*)&SMEM[8192 + bo];
            b_l[f] = *(const bf16x8*)&SMEM[12288 + bo];
        }
        #pragma unroll
        for (int i = 0; i < 4; ++i)
            #pragma unroll
            for (int j = 0; j < 4; ++j) {
                acc[i][j] = mfma16(a_h[i], b_h[j], acc[i][j]);
                acc[i][j] = mfma16(a_h[i], b_l[j], acc[i][j]);
                acc[i][j] = mfma16(a_l[i], b_h[j], acc[i][j]);
            }
    }
    const int mo = (w >> 1) * 64, no = (w & 1) * 64;
    #pragma unroll
    for (int i = 0; i < 4; ++i)
        #pragma unroll
        for (int e = 0; e < 4; ++e) {
            const int row = m0 + mo + i * 16 + l16 * 4 + e;
            #pragma unroll
            for (int j = 0; j < 4; ++j)
                out[(size_t)row * 1024 + n0 + no + j * 16 + l15] = acc[i][j][e];
        }
}

extern "C" void kernel_launch(void* const* d_in, const int* in_sizes, int n_in,
                              void* d_out, int out_size, void* d_ws, size_t ws_size,
                              hipStream_t stream)
{
    const float* x  = (const float*)d_in[0];
    const float* Wq = (const float*)d_in[1];
    const float* Wk = (const float*)d_in[2];
    const float* Wv = (const float*)d_in[3];
    const float* Wo = (const float*)d_in[4];
    float* out = (float*)d_out;

    char* ws = (char*)d_ws;
    const size_t MB = (size_t)1 << 20;
    u16* xhi  = (u16*)(ws +  0 * MB);   // 8 MB, reused as attn-out hi
    u16* xlo  = (u16*)(ws +  8 * MB);   // 8 MB, reused as attn-out lo
    u16* whi  = (u16*)(ws + 16 * MB);   // 8 MB: [4][1024][1024] q,k,v,o
    u16* wlo  = (u16*)(ws + 24 * MB);   // 8 MB
    u16* qhi  = (u16*)(ws + 32 * MB);
    u16* qlo  = (u16*)(ws + 40 * MB);
    u16* khi  = (u16*)(ws + 48 * MB);
    u16* klo  = (u16*)(ws + 56 * MB);
    u16* vthi = (u16*)(ws + 64 * MB);   // [bh][d][s]
    u16* vtlo = (u16*)(ws + 72 * MB);   // total 80 MB

    split_convert<<<8192, 256, 0, stream>>>(x, Wq, Wk, Wv, Wo, xhi, xlo, whi, wlo);
    qkv_mfma<<<dim3(12, 16), 512, 0, stream>>>(xhi, xlo, whi, wlo,
                                               qhi, qlo, khi, klo, vthi, vtlo);
    attn_mfma<<<dim3(32, NBH), 256, 0, stream>>>(qhi, qlo, khi, klo, vthi, vtlo,
                                                 xhi, xlo);
    proj_mfma<<<dim3(32, 8), 256, 0, stream>>>(xhi, xlo,
                                               whi + ((size_t)3 << 20), wlo + ((size_t)3 << 20),
                                               out);
}

// Round 11
// 523.566 us; speedup vs baseline: 1.1191x; 1.1191x over previous
//
#include <hip/hip_runtime.h>
#include <math.h>
#include <stdint.h>

// AttentionMC on MI355X: x(2,2048,1024) fp32; Wq/Wk/Wv/Wo(1024,1024) fp32.
// Split-bf16 (hi/lo, 3-term) MFMA. absmax 9.77e-4 (passed R3/R5/R6/R8/R9).
// R10: WRITE_SIZE shown to be time-proportional (broken on gfx950) - discard.
// Real signal: SQ_LDS_BANK_CONFLICT 6.29M invariant = fragment ds_read_b128
// 8-way conflicts (row stride 64B = 16 banks, rows alias pairwise).
// Fix: pad GEMM LDS row stride 32->40 u16 (80B, 16B-aligned, 2-way = free).
// qkv reverted to R6 mapping (best measured, 272us); attn/proj keep R8 swizzles.
// Pipeline: split_convert -> qkv_mfma(+RoPE, +V^T) -> attn_mfma -> proj_mfma.
// ws (80 MB): xhi xlo | whi wlo | qhi qlo khi klo | vthi vtlo
//   (xhi/xlo reused as attn-out hi/lo after qkv consumes x).

#define S_LEN 2048
#define NHEAD 16
#define HDIM  64
#define NBH   32
#define RS    40   // padded LDS row stride in u16 (80 B)

typedef __attribute__((ext_vector_type(8))) short  bf16x8;
typedef __attribute__((ext_vector_type(4))) float  f32x4;
typedef unsigned short u16;
typedef unsigned int   u32;

__device__ __forceinline__ u16 f2bf(float f) {          // RNE fp32->bf16 bits
    u32 u = __float_as_uint(f);
    return (u16)((u + 0x7FFFu + ((u >> 16) & 1u)) >> 16);
}
__device__ __forceinline__ float bf2f(u16 s) {
    return __uint_as_float(((u32)s) << 16);
}
__device__ __forceinline__ f32x4 mfma16(bf16x8 a, bf16x8 b, f32x4 c) {
    return __builtin_amdgcn_mfma_f32_16x16x32_bf16(a, b, c, 0, 0, 0);
}

// ---------------- 1. fp32 -> bf16 hi/lo split for x and all weights ----------------
__global__ __launch_bounds__(256)
void split_convert(const float* __restrict__ x,
                   const float* __restrict__ Wq, const float* __restrict__ Wk,
                   const float* __restrict__ Wv, const float* __restrict__ Wo,
                   u16* __restrict__ xhi, u16* __restrict__ xlo,
                   u16* __restrict__ whi, u16* __restrict__ wlo)
{
    const int g = blockIdx.x * 256 + threadIdx.x;   // float4 index, 2M total
    const float* src; u16 *dhi, *dlo; int loc;
    if (g < 1048576) { src = x; dhi = xhi; dlo = xlo; loc = g; }
    else {
        const int r = g - 1048576;
        const int wsel = r >> 18;                   // 256K float4 per weight
        loc = r & 262143;
        src = (wsel == 0) ? Wq : (wsel == 1) ? Wk : (wsel == 2) ? Wv : Wo;
        dhi = whi + ((size_t)wsel << 20);
        dlo = wlo + ((size_t)wsel << 20);
    }
    const float4 v = reinterpret_cast<const float4*>(src)[loc];
    ushort4 hv, lv;
    hv.x = f2bf(v.x); lv.x = f2bf(v.x - bf2f(hv.x));
    hv.y = f2bf(v.y); lv.y = f2bf(v.y - bf2f(hv.y));
    hv.z = f2bf(v.z); lv.z = f2bf(v.z - bf2f(hv.z));
    hv.w = f2bf(v.w); lv.w = f2bf(v.w - bf2f(hv.w));
    reinterpret_cast<ushort4*>(dhi)[loc] = hv;
    reinterpret_cast<ushort4*>(dlo)[loc] = lv;
}

// ---------------- 2. QKV projection GEMM (hi/lo MFMA) + RoPE + V^T epilogue ----------------
// M=4096, Nglobal=3072 (q|k|v), K=1024. 128x128 tile, BK=32, 4 waves (64x64 each).
// Reg-staged LDS fill, 2-phase prefetch. LDS [128][RS=40] u16 per array:
// Ah@0 Al@5120 Bh@10240 Bl@15360 (u16), 40960 B total. Bank-conflict-free.
__global__ __launch_bounds__(256)
void qkv_mfma(const u16* __restrict__ xhi, const u16* __restrict__ xlo,
              const u16* __restrict__ whi, const u16* __restrict__ wlo,
              u16* __restrict__ qhi, u16* __restrict__ qlo,
              u16* __restrict__ khi, u16* __restrict__ klo,
              u16* __restrict__ vthi, u16* __restrict__ vtlo)
{
    __shared__ __align__(16) u16 SMEM[20480];   // 40960 B
    const int tid = threadIdx.x, lane = tid & 63, w = tid >> 6;
    const int l15 = lane & 15, l16 = lane >> 4;
    const int m0 = blockIdx.x * 128;
    const int ng = blockIdx.y * 128;
    const int tsel = ng >> 10;               // 0=q 1=k 2=v
    const int nloc0 = ng & 1023;
    const u16* __restrict__ Wh = whi + ((size_t)tsel << 20);
    const u16* __restrict__ Wl = wlo + ((size_t)tsel << 20);

    // staging geometry: thread stages rows {tid>>2, +64}, 16B at u16-col (tid&3)*8
    const int r0 = tid >> 2, r1 = r0 + 64;
    const int c0 = (tid & 3) * 8;

    f32x4 acc[4][4];
    #pragma unroll
    for (int i = 0; i < 4; ++i)
        #pragma unroll
        for (int j = 0; j < 4; ++j) acc[i][j] = (f32x4){0.f, 0.f, 0.f, 0.f};

    // prologue: load k-tile 0 into regs
    uint4 Ah0, Ah1, Al0, Al1, Bh0, Bh1, Bl0, Bl1;
    {
        const size_t a0 = (size_t)(m0 + r0) * 1024 + c0;
        const size_t a1 = (size_t)(m0 + r1) * 1024 + c0;
        const size_t b0 = (size_t)(nloc0 + r0) * 1024 + c0;
        const size_t b1 = (size_t)(nloc0 + r1) * 1024 + c0;
        Ah0 = *(const uint4*)&xhi[a0]; Ah1 = *(const uint4*)&xhi[a1];
        Al0 = *(const uint4*)&xlo[a0]; Al1 = *(const uint4*)&xlo[a1];
        Bh0 = *(const uint4*)&Wh[b0];  Bh1 = *(const uint4*)&Wh[b1];
        Bl0 = *(const uint4*)&Wl[b0];  Bl1 = *(const uint4*)&Wl[b1];
    }

    for (int k0 = 0; k0 < 1024; k0 += 32) {
        __syncthreads();                          // prev tile's frag reads done
        *(uint4*)&SMEM[        r0 * RS + c0] = Ah0;
        *(uint4*)&SMEM[        r1 * RS + c0] = Ah1;
        *(uint4*)&SMEM[ 5120 + r0 * RS + c0] = Al0;
        *(uint4*)&SMEM[ 5120 + r1 * RS + c0] = Al1;
        *(uint4*)&SMEM[10240 + r0 * RS + c0] = Bh0;
        *(uint4*)&SMEM[10240 + r1 * RS + c0] = Bh1;
        *(uint4*)&SMEM[15360 + r0 * RS + c0] = Bl0;
        *(uint4*)&SMEM[15360 + r1 * RS + c0] = Bl1;
        __syncthreads();                          // tile visible to all waves
        if (k0 + 32 < 1024) {                     // prefetch next tile under MFMA
            const int kn = k0 + 32;
            const size_t a0 = (size_t)(m0 + r0) * 1024 + kn + c0;
            const size_t a1 = (size_t)(m0 + r1) * 1024 + kn + c0;
            const size_t b0 = (size_t)(nloc0 + r0) * 1024 + kn + c0;
            const size_t b1 = (size_t)(nloc0 + r1) * 1024 + kn + c0;
            Ah0 = *(const uint4*)&xhi[a0]; Ah1 = *(const uint4*)&xhi[a1];
            Al0 = *(const uint4*)&xlo[a0]; Al1 = *(const uint4*)&xlo[a1];
            Bh0 = *(const uint4*)&Wh[b0];  Bh1 = *(const uint4*)&Wh[b1];
            Bl0 = *(const uint4*)&Wl[b0];  Bl1 = *(const uint4*)&Wl[b1];
        }
        const int mo = (w >> 1) * 64, no = (w & 1) * 64;
        bf16x8 a_h[4], a_l[4], b_h[4], b_l[4];
        #pragma unroll
        for (int f = 0; f < 4; ++f) {
            const int ao = (mo + f * 16 + l15) * RS + l16 * 8;
            a_h[f] = *(const bf16x8*)&SMEM[ao];
            a_l[f] = *(const bf16x8*)&SMEM[5120 + ao];
            const int bo = (no + f * 16 + l15) * RS + l16 * 8;
            b_h[f] = *(const bf16x8*)&SMEM[10240 + bo];
            b_l[f] = *(const bf16x8*)&SMEM[15360 + bo];
        }
        #pragma unroll
        for (int i = 0; i < 4; ++i)
            #pragma unroll
            for (int j = 0; j < 4; ++j) {
                acc[i][j] = mfma16(a_h[i], b_h[j], acc[i][j]);
                acc[i][j] = mfma16(a_h[i], b_l[j], acc[i][j]);
                acc[i][j] = mfma16(a_l[i], b_h[j], acc[i][j]);
            }
    }

    // ---- epilogue: LDS-staged, fully-coalesced uint4 stores ----
    __syncthreads();                         // all waves done reading SMEM
    const int mo = (w >> 1) * 64, no = (w & 1) * 64;
    const int hh = (nloc0 + no) >> 6;        // head (wave's 64-col block is head-aligned)
    const int mrow = m0 + mo;
    const int b = mrow >> 11, sb0 = mrow & 2047;
    u16* const chunk = SMEM + w * 5120;      // 10240 B per wave

    if (tsel < 2) {
        u16* __restrict__ dh = tsel ? khi : qhi;
        u16* __restrict__ dl = tsel ? klo : qlo;
        const float scl = tsel ? 1.0f : 0.125f;   // fold 1/sqrt(hd) into q
        const float inv0 = (float)exp((double)l15        * -0.28782313662425574);
        const float inv1 = (float)exp((double)(l15 + 16) * -0.28782313662425574);
        u16* const Thi = chunk;              // [32][72]
        u16* const Tlo = chunk + 2304;
        #pragma unroll
        for (int half = 0; half < 2; ++half) {
            #pragma unroll
            for (int i2 = 0; i2 < 2; ++i2) {
                const int i = half * 2 + i2;
                #pragma unroll
                for (int e = 0; e < 4; ++e) {
                    const int rl = i2 * 16 + l16 * 4 + e;     // row within half-tile
                    const int s = sb0 + half * 32 + rl;
                    #pragma unroll
                    for (int j = 0; j < 2; ++j) {             // pair (d, d+32) = frags (j, j+2)
                        const float inv = j ? inv1 : inv0;
                        const float ang = (float)s * inv;
                        const float sn = sinf(ang), cs = cosf(ang);
                        const float x1 = acc[i][j][e], x2 = acc[i][j + 2][e];
                        const float o1 = (x1 * cs - x2 * sn) * scl;
                        const float o2 = (x1 * sn + x2 * cs) * scl;
                        const u16 h1 = f2bf(o1), h2 = f2bf(o2);
                        Thi[rl * 72 + j * 16 + l15]       = h1;
                        Tlo[rl * 72 + j * 16 + l15]       = f2bf(o1 - bf2f(h1));
                        Thi[rl * 72 + (j + 2) * 16 + l15] = h2;
                        Tlo[rl * 72 + (j + 2) * 16 + l15] = f2bf(o2 - bf2f(h2));
                    }
                }
            }
            #pragma unroll
            for (int p = 0; p < 4; ++p) {    // 32 rows x 128B, full lines
                const int slot = p * 64 + lane;
                const int rr = slot >> 3, c8 = (slot & 7) * 8;
                const size_t ga = (((size_t)(b * NHEAD + hh) * S_LEN) + sb0 + half * 32 + rr) * HDIM + c8;
                *(uint4*)&dh[ga] = *(const uint4*)&Thi[rr * 72 + c8];
                *(uint4*)&dl[ga] = *(const uint4*)&Tlo[rr * 72 + c8];
            }
        }
    } else {
        // V: stage transposed (d-major) and store directly to V^T [bh][d][s]
        u16* const Thi = chunk;              // [64][40]
        u16* const Tlo = chunk + 2560;
        #pragma unroll
        for (int half = 0; half < 2; ++half) {
            #pragma unroll
            for (int i2 = 0; i2 < 2; ++i2) {
                const int i = half * 2 + i2;
                #pragma unroll
                for (int e = 0; e < 4; ++e) {
                    const int rl = i2 * 16 + l16 * 4 + e;     // s within half-tile
                    #pragma unroll
                    for (int j = 0; j < 4; ++j) {
                        const float o = acc[i][j][e];
                        const u16 hb = f2bf(o);
                        Thi[(j * 16 + l15) * 40 + rl] = hb;
                        Tlo[(j * 16 + l15) * 40 + rl] = f2bf(o - bf2f(hb));
                    }
                }
            }
            #pragma unroll
            for (int p = 0; p < 4; ++p) {    // 64 d-rows x 64B
                const int slot = p * 64 + lane;
                const int dd = slot >> 2, s8 = (slot & 3) * 8;
                const size_t ga = (((size_t)(b * NHEAD + hh) * HDIM) + dd) * S_LEN + sb0 + half * 32 + s8;
                *(uint4*)&vthi[ga] = *(const uint4*)&Thi[dd * 40 + s8];
                *(uint4*)&vtlo[ga] = *(const uint4*)&Tlo[dd * 40 + s8];
            }
        }
    }
}

// ---------------- 3. causal flash attention (hi/lo MFMA) ----------------
// grid (32,32), 256 thr = 4 waves, wave w owns q-rows [qt*64+16w, +16).
// XCD swizzle: XCD k owns heads {4k..4k+3}; within head, qt longest-first.
// LDS stride 72 u16 already 2-way-free. 54272 B flat: KH|KL|VH|VL | PW.
__global__ __launch_bounds__(256)
void attn_mfma(const u16* __restrict__ qhi, const u16* __restrict__ qlo,
               const u16* __restrict__ khi, const u16* __restrict__ klo,
               const u16* __restrict__ vthi, const u16* __restrict__ vtlo,
               u16* __restrict__ ohi, u16* __restrict__ olo)
{
    __shared__ __align__(16) u16 AS[27136];
    u16* const KH = AS;              // 4608 u16
    u16* const KL = AS + 4608;
    u16* const VH = AS + 9216;
    u16* const VL = AS + 13824;
    float* const PW = (float*)(AS + 18432);   // [4][16][68]
    const int tid = threadIdx.x, lane = tid & 63, w = tid >> 6;
    const int l15 = lane & 15, l16 = lane >> 4;
    // --- XCD-aware bijective remap (1024 = 8 XCD x 128) ---
    const int lin = blockIdx.y * 32 + blockIdx.x;
    const int xcd = lin & 7, idx = lin >> 3;      // idx 0..127
    const int bh = xcd * 4 + (idx >> 5);          // head 0..31 (XCD-striped)
    const int qt = 31 - (idx & 31);               // longest blocks first
    const size_t sbase = (size_t)bh * S_LEN * HDIM;   // [bh][s][d]
    const size_t dbase = (size_t)bh * HDIM * S_LEN;   // [bh][d][s]
    float* const pw = PW + w * 1088;

    // Q fragments hoisted for the whole kernel (q pre-scaled by 1/8)
    bf16x8 q_h[2], q_l[2];
    {
        const int s = qt * 64 + w * 16 + l15;
        #pragma unroll
        for (int ks = 0; ks < 2; ++ks) {
            const size_t ga = sbase + (size_t)s * HDIM + ks * 32 + l16 * 8;
            q_h[ks] = *(const bf16x8*)&qhi[ga];
            q_l[ks] = *(const bf16x8*)&qlo[ga];
        }
    }

    f32x4 oacc[4];
    #pragma unroll
    for (int t = 0; t < 4; ++t) oacc[t] = (f32x4){0.f, 0.f, 0.f, 0.f};
    float m_i[4], l_i[4];
    #pragma unroll
    for (int e = 0; e < 4; ++e) { m_i[e] = -INFINITY; l_i[e] = 0.f; }

    for (int kt = 0; kt <= qt; ++kt) {
        __syncthreads();                       // protect LDS K/V reuse
        #pragma unroll
        for (int p = 0; p < 2; ++p) {          // reg-stage K and V^T tiles
            const int c = tid + p * 256;       // 512 16B-chunks per tensor
            const int r = c >> 3, dc = (c & 7) * 8;
            const size_t gk = sbase + (size_t)(kt * 64 + r) * HDIM + dc;
            *(uint4*)&KH[r * 72 + dc] = *(const uint4*)&khi[gk];
            *(uint4*)&KL[r * 72 + dc] = *(const uint4*)&klo[gk];
            const size_t gv = dbase + (size_t)r * S_LEN + kt * 64 + dc;
            *(uint4*)&VH[r * 72 + dc] = *(const uint4*)&vthi[gv];
            *(uint4*)&VL[r * 72 + dc] = *(const uint4*)&vtlo[gv];
        }
        __syncthreads();

        // QK^T: scores[16 q-rows][64 k-cols] per wave
        f32x4 st[4];
        #pragma unroll
        for (int t = 0; t < 4; ++t) st[t] = (f32x4){0.f, 0.f, 0.f, 0.f};
        #pragma unroll
        for (int t = 0; t < 4; ++t)
            #pragma unroll
            for (int ks = 0; ks < 2; ++ks) {
                const bf16x8 kf_h = *(const bf16x8*)&KH[(t * 16 + l15) * 72 + ks * 32 + l16 * 8];
                const bf16x8 kf_l = *(const bf16x8*)&KL[(t * 16 + l15) * 72 + ks * 32 + l16 * 8];
                st[t] = mfma16(q_h[ks], kf_h, st[t]);
                st[t] = mfma16(q_h[ks], kf_l, st[t]);
                st[t] = mfma16(q_l[ks], kf_h, st[t]);
            }
        if (kt == qt) {                        // causal mask inside diagonal tile
            #pragma unroll
            for (int t = 0; t < 4; ++t)
                #pragma unroll
                for (int e = 0; e < 4; ++e)
                    if (t * 16 + l15 > w * 16 + l16 * 4 + e) st[t][e] = -1e30f;
        }
        // online softmax (rows live in D-layout: row = 4*l16+e, 16 lanes share a row)
        #pragma unroll
        for (int e = 0; e < 4; ++e) {
            float mx = fmaxf(fmaxf(st[0][e], st[1][e]), fmaxf(st[2][e], st[3][e]));
            #pragma unroll
            for (int msk = 8; msk >= 1; msk >>= 1) mx = fmaxf(mx, __shfl_xor(mx, msk));
            const float mn = fmaxf(m_i[e], mx);
            const float scl = __expf(m_i[e] - mn);
            float rs = 0.f;
            #pragma unroll
            for (int t = 0; t < 4; ++t) {
                const float p = __expf(st[t][e] - mn);
                st[t][e] = p; rs += p;
            }
            #pragma unroll
            for (int msk = 8; msk >= 1; msk >>= 1) rs += __shfl_xor(rs, msk);
            l_i[e] = l_i[e] * scl + rs;
            m_i[e] = mn;
            #pragma unroll
            for (int t = 0; t < 4; ++t) oacc[t][e] *= scl;
        }
        // P: D-layout regs -> wave-private LDS -> A-operand layout + hi/lo split
        #pragma unroll
        for (int t = 0; t < 4; ++t)
            #pragma unroll
            for (int e = 0; e < 4; ++e)
                pw[(l16 * 4 + e) * 68 + t * 16 + l15] = st[t][e];
        bf16x8 p_h[2], p_l[2];
        #pragma unroll
        for (int ks = 0; ks < 2; ++ks) {
            float pf[8];
            *(f32x4*)&pf[0] = *(const f32x4*)&pw[l15 * 68 + ks * 32 + l16 * 8];
            *(f32x4*)&pf[4] = *(const f32x4*)&pw[l15 * 68 + ks * 32 + l16 * 8 + 4];
            #pragma unroll
            for (int u = 0; u < 8; ++u) {
                const u16 hb = f2bf(pf[u]);
                p_h[ks][u] = (short)hb;
                p_l[ks][u] = (short)f2bf(pf[u] - bf2f(hb));
            }
        }
        // PV: out[m][d] += P[m][n] V[n][d]  (V^T tile, n contiguous)
        #pragma unroll
        for (int t = 0; t < 4; ++t)
            #pragma unroll
            for (int ks = 0; ks < 2; ++ks) {
                const bf16x8 vf_h = *(const bf16x8*)&VH[(t * 16 + l15) * 72 + ks * 32 + l16 * 8];
                const bf16x8 vf_l = *(const bf16x8*)&VL[(t * 16 + l15) * 72 + ks * 32 + l16 * 8];
                oacc[t] = mfma16(p_h[ks], vf_h, oacc[t]);
                oacc[t] = mfma16(p_h[ks], vf_l, oacc[t]);
                oacc[t] = mfma16(p_l[ks], vf_h, oacc[t]);
            }
    }
    // ---- epilogue: normalize, split hi/lo, LDS-staged coalesced store ----
    __syncthreads();                          // K/V LDS dead; alias staging over it
    u16* const Ohi = AS + w * 2304;           // [16][72] per wave
    u16* const Olo = Ohi + 1152;
    #pragma unroll
    for (int e = 0; e < 4; ++e) {
        const float invl = 1.f / l_i[e];
        const int rl = l16 * 4 + e;
        #pragma unroll
        for (int t = 0; t < 4; ++t) {
            const float o = oacc[t][e] * invl;
            const u16 hb = f2bf(o);
            Ohi[rl * 72 + t * 16 + l15] = hb;
            Olo[rl * 72 + t * 16 + l15] = f2bf(o - bf2f(hb));
        }
    }
    #pragma unroll
    for (int p = 0; p < 2; ++p) {             // 16 rows x 128B, full lines
        const int slot = p * 64 + lane;
        const int rr = slot >> 3, c8 = (slot & 7) * 8;
        const size_t ga = sbase + (size_t)(qt * 64 + w * 16 + rr) * HDIM + c8;
        *(uint4*)&ohi[ga] = *(const uint4*)&Ohi[rr * 72 + c8];
        *(uint4*)&olo[ga] = *(const uint4*)&Olo[rr * 72 + c8];
    }
}

// ---------------- 4. output projection: out = attn_out @ Wo^T (fp32 out) ----------------
// Reg-staged LDS fill (RS=40 padded), 2-phase prefetch. XCD swizzle: XCD k owns
// m-blocks {4k..4k+3}; within XCD consecutive blocks share the A-slab.
__global__ __launch_bounds__(256)
void proj_mfma(const u16* __restrict__ ahi, const u16* __restrict__ alo,
               const u16* __restrict__ wohi, const u16* __restrict__ wolo,
               float* __restrict__ out)
{
    __shared__ __align__(16) u16 SMEM[20480];   // Ah@0 Al@5120 Bh@10240 Bl@15360
    const int tid = threadIdx.x, lane = tid & 63, w = tid >> 6;
    const int l15 = lane & 15, l16 = lane >> 4;
    // --- XCD-aware bijective remap (256 = 8 XCD x 32) ---
    const int lin = blockIdx.y * 32 + blockIdx.x;
    const int xcd = lin & 7, idx = lin >> 3;     // idx 0..31
    const int mb = xcd * 4 + (idx >> 3);         // m-block 0..31 (XCD-striped)
    const int nb = idx & 7;                      // n-block 0..7 (A-slab hot)
    const int m0 = mb * 128, n0 = nb * 128;

    const int r0 = tid >> 2, r1 = r0 + 64;
    const int c0 = (tid & 3) * 8;
    // A-row geometry is k-independent
    const int ri0 = m0 + r0, ri1 = m0 + r1;
    const int ab0 = ri0 >> 11, as0 = ri0 & 2047;
    const int ab1 = ri1 >> 11, as1 = ri1 & 2047;

    f32x4 acc[4][4];
    #pragma unroll
    for (int i = 0; i < 4; ++i)
        #pragma unroll
        for (int j = 0; j < 4; ++j) acc[i][j] = (f32x4){0.f, 0.f, 0.f, 0.f};

    uint4 Ah0, Ah1, Al0, Al1, Bh0, Bh1, Bl0, Bl1;
    {
        const int kc = c0;                    // k0 = 0
        const int hh = kc >> 6, dd = kc & 63;
        const size_t a0 = ((size_t)(ab0 * NHEAD + hh) * S_LEN + as0) * HDIM + dd;
        const size_t a1 = ((size_t)(ab1 * NHEAD + hh) * S_LEN + as1) * HDIM + dd;
        const size_t b0 = (size_t)(n0 + r0) * 1024 + c0;
        const size_t b1 = (size_t)(n0 + r1) * 1024 + c0;
        Ah0 = *(const uint4*)&ahi[a0];  Ah1 = *(const uint4*)&ahi[a1];
        Al0 = *(const uint4*)&alo[a0];  Al1 = *(const uint4*)&alo[a1];
        Bh0 = *(const uint4*)&wohi[b0]; Bh1 = *(const uint4*)&wohi[b1];
        Bl0 = *(const uint4*)&wolo[b0]; Bl1 = *(const uint4*)&wolo[b1];
    }

    for (int k0 = 0; k0 < 1024; k0 += 32) {
        __syncthreads();
        *(uint4*)&SMEM[        r0 * RS + c0] = Ah0;
        *(uint4*)&SMEM[        r1 * RS + c0] = Ah1;
        *(uint4*)&SMEM[ 5120 + r0 * RS + c0] = Al0;
        *(uint4*)&SMEM[ 5120 + r1 * RS + c0] = Al1;
        *(uint4*)&SMEM[10240 + r0 * RS + c0] = Bh0;
        *(uint4*)&SMEM[10240 + r1 * RS + c0] = Bh1;
        *(uint4*)&SMEM[15360 + r0 * RS + c0] = Bl0;
        *(uint4*)&SMEM[15360 + r1 * RS + c0] = Bl1;
        __syncthreads();
        if (k0 + 32 < 1024) {
            const int kc = k0 + 32 + c0;
            const int hh = kc >> 6, dd = kc & 63;
            const size_t a0 = ((size_t)(ab0 * NHEAD + hh) * S_LEN + as0) * HDIM + dd;
            const size_t a1 = ((size_t)(ab1 * NHEAD + hh) * S_LEN + as1) * HDIM + dd;
            const size_t b0 = (size_t)(n0 + r0) * 1024 + k0 + 32 + c0;
            const size_t b1 = (size_t)(n0 + r1) * 1024 + k0 + 32 + c0;
            Ah0 = *(const uint4*)&ahi[a0];  Ah1 = *(const uint4*)&ahi[a1];
            Al0 = *(const uint4*)&alo[a0];  Al1 = *(const uint4*)&alo[a1];
            Bh0 = *(const uint4*)&wohi[b0]; Bh1 = *(const uint4*)&wohi[b1];
            Bl0 = *(const uint4*)&wolo[b0]; Bl1 = *(const uint4*)&wolo[b1];
        }
        const int mo = (w >> 1) * 64, no = (w & 1) * 64;
        bf16x8 a_h[4], a_l[4], b_h[4], b_l[4];
        #pragma unroll
        for (int f = 0; f < 4; ++f) {
            const int ao = (mo + f * 16 + l15) * RS + l16 * 8;
            a_h[f] = *(const bf16x8*)&SMEM[ao];
            a_l[f] = *(const bf16x8*)&SMEM[5120 + ao];
            const int bo = (no + f * 16 + l15) * RS + l16 * 8;
            b_h[f] = *(const bf16x8*)&SMEM[10240 + bo];
            b_l[f] = *(const bf16x8*)&SMEM[15360 + bo];
        }
        #pragma unroll
        for (int i = 0; i < 4; ++i)
            #pragma unroll
            for (int j = 0; j < 4; ++j) {
                acc[i][j] = mfma16(a_h[i], b_h[j], acc[i][j]);
                acc[i][j] = mfma16(a_h[i], b_l[j], acc[i][j]);
                acc[i][j] = mfma16(a_l[i], b_h[j], acc[i][j]);
            }
    }
    const int mo = (w >> 1) * 64, no = (w & 1) * 64;
    #pragma unroll
    for (int i = 0; i < 4; ++i)
        #pragma unroll
        for (int e = 0; e < 4; ++e) {
            const int row = m0 + mo + i * 16 + l16 * 4 + e;
            #pragma unroll
            for (int j = 0; j < 4; ++j)
                out[(size_t)row * 1024 + n0 + no + j * 16 + l15] = acc[i][j][e];
        }
}

extern "C" void kernel_launch(void* const* d_in, const int* in_sizes, int n_in,
                              void* d_out, int out_size, void* d_ws, size_t ws_size,
                              hipStream_t stream)
{
    const float* x  = (const float*)d_in[0];
    const float* Wq = (const float*)d_in[1];
    const float* Wk = (const float*)d_in[2];
    const float* Wv = (const float*)d_in[3];
    const float* Wo = (const float*)d_in[4];
    float* out = (float*)d_out;

    char* ws = (char*)d_ws;
    const size_t MB = (size_t)1 << 20;
    u16* xhi  = (u16*)(ws +  0 * MB);   // 8 MB, reused as attn-out hi
    u16* xlo  = (u16*)(ws +  8 * MB);   // 8 MB, reused as attn-out lo
    u16* whi  = (u16*)(ws + 16 * MB);   // 8 MB: [4][1024][1024] q,k,v,o
    u16* wlo  = (u16*)(ws + 24 * MB);   // 8 MB
    u16* qhi  = (u16*)(ws + 32 * MB);
    u16* qlo  = (u16*)(ws + 40 * MB);
    u16* khi  = (u16*)(ws + 48 * MB);
    u16* klo  = (u16*)(ws + 56 * MB);
    u16* vthi = (u16*)(ws + 64 * MB);   // [bh][d][s]
    u16* vtlo = (u16*)(ws + 72 * MB);   // total 80 MB

    split_convert<<<8192, 256, 0, stream>>>(x, Wq, Wk, Wv, Wo, xhi, xlo, whi, wlo);
    qkv_mfma<<<dim3(32, 24), 256, 0, stream>>>(xhi, xlo, whi, wlo,
                                               qhi, qlo, khi, klo, vthi, vtlo);
    attn_mfma<<<dim3(32, NBH), 256, 0, stream>>>(qhi, qlo, khi, klo, vthi, vtlo,
                                                 xhi, xlo);
    proj_mfma<<<dim3(32, 8), 256, 0, stream>>>(xhi, xlo,
                                               whi + ((size_t)3 << 20), wlo + ((size_t)3 << 20),
                                               out);
}